// Round 1
// baseline (50.254 us; speedup 1.0000x reference)
//
#include <hip/hip_runtime.h>
#include <hip/hip_bf16.h>

// Problem constants (from reference): N=8, C=4096, H=768, O=768, K=1024
#define N_B 8
#define C_C 4096
#define H_H 768
#define O_O 768
#define K_K 1024
#define M_TOT (N_B * K_K)        // 8192 gathered rows

#define BM 128
#define BN 128
#define BK 64
#define NT (H_H / BK)            // 12 K-steps
#define GBM (M_TOT / BM)         // 64
#define GBN (O_O / BN)           // 6
#define GEMM_BLOCKS (GBM * GBN)  // 384
#define ZBLOCKS 1024
#define TOT_ROWS (N_B * C_C)     // 32768

typedef __attribute__((ext_vector_type(8))) short short8;
typedef __attribute__((ext_vector_type(4))) float f32x4;
typedef __attribute__((ext_vector_type(4))) unsigned short ushort4v;

__device__ __forceinline__ unsigned short f2bf(float f) {
    union { float f; unsigned int u; } v; v.f = f;
    unsigned int r = v.u + 0x7FFFu + ((v.u >> 16) & 1u);  // RNE
    return (unsigned short)(r >> 16);
}

__global__ void build_mask_kernel(const int* __restrict__ cidx,
                                  unsigned char* __restrict__ mask) {
    int m = blockIdx.x * 256 + threadIdx.x;
    if (m < M_TOT) {
        int n = m >> 10;                 // m / K_K
        mask[n * C_C + cidx[m]] = 1;
    }
}

// Fused kernel: blocks [0, GEMM_BLOCKS) compute the gathered GEMM and scatter
// rows (+bias). Blocks [GEMM_BLOCKS, GEMM_BLOCKS+ZBLOCKS) zero the
// non-selected output rows (mask==0). Row sets are disjoint -> no race.
__global__ __launch_bounds__(256, 2)
void sparse_linear_kernel(const float* __restrict__ x,
                          const float* __restrict__ w,
                          const float* __restrict__ bias,
                          const int* __restrict__ cidx,
                          const unsigned char* __restrict__ mask,
                          float* __restrict__ out)
{
    __shared__ char lds[2 * BM * BK * 2];   // As (16KB) + Bs (16KB), bf16, swizzled

    if (blockIdx.x >= GEMM_BLOCKS) {
        // ---- zero-writer path: rows with mask==0 ----
        int zb = blockIdx.x - GEMM_BLOCKS;
        const int ngroups = TOT_ROWS / 4;          // 8192 groups of 4 rows
        for (int g = zb; g < ngroups; g += ZBLOCKS) {
            #pragma unroll
            for (int i = 0; i < 3; ++i) {
                int item = threadIdx.x + i * 256;   // 0..767 = 4 rows x 192 float4
                int r = item / 192;
                int c4 = item - r * 192;
                int row = g * 4 + r;
                if (!mask[row]) {
                    f32x4 z = {0.f, 0.f, 0.f, 0.f};
                    *reinterpret_cast<f32x4*>(out + (size_t)row * O_O + (size_t)c4 * 4) = z;
                }
            }
        }
        return;
    }

    // ---- GEMM path ----
    char* Asb = lds;                 // [128][64] bf16, row stride 128 B
    char* Bsb = lds + BM * BK * 2;

    const int tid  = threadIdx.x;
    const int lane = tid & 63;
    const int wid  = tid >> 6;
    const int wr   = wid >> 1;       // wave row 0..1 (64-row half)
    const int wc   = wid & 1;        // wave col 0..1 (64-col half)

    const int bm = blockIdx.x / GBN;
    const int bn = blockIdx.x % GBN;

    const int sr = tid >> 4;         // staging row-in-pass 0..15
    const int sc = tid & 15;         // staging float4 col 0..15 (64 floats)

    // Per-thread source element offsets (fixed across K-steps)
    int aoff[8];
    int boff[8];
    #pragma unroll
    for (int p = 0; p < 8; ++p) {
        int row = p * 16 + sr;                  // 0..127
        int m = bm * BM + row;
        int n = m >> 10;
        int src = cidx[m];
        aoff[p] = (n * C_C + src) * H_H + sc * 4;
        boff[p] = (bn * BN + row) * H_H + sc * 4;
    }

    // LDS write swizzle: byte = row*128 + ((sc*8) ^ ((row&7)<<4)); row&7 == sr&7
    const int wsw = (sc * 8) ^ ((sr & 7) << 4);

    // Prologue: load K-step 0 into registers
    f32x4 av[8], bv[8];
    #pragma unroll
    for (int p = 0; p < 8; ++p) {
        av[p] = *reinterpret_cast<const f32x4*>(x + aoff[p]);
        bv[p] = *reinterpret_cast<const f32x4*>(w + boff[p]);
    }

    f32x4 acc[4][4];
    #pragma unroll
    for (int i = 0; i < 4; ++i)
        #pragma unroll
        for (int j = 0; j < 4; ++j)
            acc[i][j] = (f32x4){0.f, 0.f, 0.f, 0.f};

    const int frow = lane & 15;            // fragment row within 16
    const int fkb  = (lane >> 4) * 16;     // k-part byte offset (8 bf16 = 16 B)

    for (int kt = 0; kt < NT; ++kt) {
        __syncthreads();                    // previous compute done; LDS free
        #pragma unroll
        for (int p = 0; p < 8; ++p) {
            int row = p * 16 + sr;
            ushort4v pa, pb;
            pa.x = f2bf(av[p].x); pa.y = f2bf(av[p].y);
            pa.z = f2bf(av[p].z); pa.w = f2bf(av[p].w);
            pb.x = f2bf(bv[p].x); pb.y = f2bf(bv[p].y);
            pb.z = f2bf(bv[p].z); pb.w = f2bf(bv[p].w);
            *reinterpret_cast<ushort4v*>(Asb + row * 128 + wsw) = pa;
            *reinterpret_cast<ushort4v*>(Bsb + row * 128 + wsw) = pb;
        }
        __syncthreads();

        // T14: issue next tile's global loads before compute (latency hidden)
        if (kt + 1 < NT) {
            const int kbase = (kt + 1) * BK;
            #pragma unroll
            for (int p = 0; p < 8; ++p) {
                av[p] = *reinterpret_cast<const f32x4*>(x + aoff[p] + kbase);
                bv[p] = *reinterpret_cast<const f32x4*>(w + boff[p] + kbase);
            }
        }

        #pragma unroll
        for (int kk = 0; kk < 2; ++kk) {
            short8 af[4], bf_[4];
            const int kbyte = kk * 64 + fkb;      // 32 elems * 2B per kk
            #pragma unroll
            for (int mi = 0; mi < 4; ++mi) {
                int row = wr * 64 + mi * 16 + frow;
                af[mi] = *reinterpret_cast<const short8*>(
                    Asb + row * 128 + (kbyte ^ ((row & 7) << 4)));
            }
            #pragma unroll
            for (int nj = 0; nj < 4; ++nj) {
                int row = wc * 64 + nj * 16 + frow;
                bf_[nj] = *reinterpret_cast<const short8*>(
                    Bsb + row * 128 + (kbyte ^ ((row & 7) << 4)));
            }
            #pragma unroll
            for (int mi = 0; mi < 4; ++mi)
                #pragma unroll
                for (int nj = 0; nj < 4; ++nj)
                    acc[mi][nj] = __builtin_amdgcn_mfma_f32_16x16x32_bf16(
                        af[mi], bf_[nj], acc[mi][nj], 0, 0, 0);
        }
    }

    // ---- epilogue: scatter rows with bias ----
    const int cbase = bn * BN + wc * 64 + frow;   // output col base (lane&15 part)
    float biasv[4];
    #pragma unroll
    for (int nj = 0; nj < 4; ++nj) biasv[nj] = bias[cbase + nj * 16];

    #pragma unroll
    for (int mi = 0; mi < 4; ++mi) {
        #pragma unroll
        for (int r = 0; r < 4; ++r) {
            int grow = bm * BM + wr * 64 + mi * 16 + (lane >> 4) * 4 + r;
            int n = grow >> 10;
            int src = cidx[grow];
            size_t obase = ((size_t)(n * C_C + src)) * O_O;
            #pragma unroll
            for (int nj = 0; nj < 4; ++nj) {
                out[obase + cbase + nj * 16] = acc[mi][nj][r] + biasv[nj];
            }
        }
    }
}

extern "C" void kernel_launch(void* const* d_in, const int* in_sizes, int n_in,
                              void* d_out, int out_size, void* d_ws, size_t ws_size,
                              hipStream_t stream) {
    const float* x    = (const float*)d_in[0];
    const float* w    = (const float*)d_in[1];
    const float* bias = (const float*)d_in[2];
    const int*   cidx = (const int*)d_in[3];
    float* out = (float*)d_out;
    unsigned char* mask = (unsigned char*)d_ws;   // 32768 bytes

    hipMemsetAsync(mask, 0, TOT_ROWS, stream);
    build_mask_kernel<<<(M_TOT + 255) / 256, 256, 0, stream>>>(cidx, mask);
    sparse_linear_kernel<<<GEMM_BLOCKS + ZBLOCKS, 256, 0, stream>>>(
        x, w, bias, cidx, mask, out);
}

// Round 2
// 47.811 us; speedup vs baseline: 1.0511x; 1.0511x over previous
//
#include <hip/hip_runtime.h>
#include <hip/hip_bf16.h>

// Problem constants: N=8, C=4096, H=768, O=768, K=1024
#define N_B 8
#define C_C 4096
#define H_H 768
#define O_O 768
#define K_K 1024
#define M_TOT (N_B * K_K)        // 8192 gathered rows
#define TOT_ROWS (N_B * C_C)     // 32768 output rows

#define BM 64
#define BN 128
#define BK 64
#define NT (H_H / BK)            // 12 K-steps
#define GBM (M_TOT / BM)         // 128
#define GBN (O_O / BN)           // 6
#define GEMM_BLOCKS (GBM * GBN)  // 768 = 3 blocks/CU exactly
#define ZBLOCKS 1280
#define XCD_CHUNK (GEMM_BLOCKS / 8)  // 96

typedef __attribute__((ext_vector_type(8))) short short8;
typedef __attribute__((ext_vector_type(4))) float f32x4;
typedef __attribute__((ext_vector_type(4))) unsigned short ushort4v;

__device__ __forceinline__ unsigned short f2bf(float f) {
    union { float f; unsigned int u; } v; v.f = f;
    unsigned int r = v.u + 0x7FFFu + ((v.u >> 16) & 1u);  // RNE
    return (unsigned short)(r >> 16);
}

// One fused kernel.
// Blocks [0, GEMM_BLOCKS): gathered GEMM, scatter rows (+bias).
// Blocks [GEMM_BLOCKS, +ZBLOCKS): zero rows NOT in cidx (binary search on the
// sorted per-batch index list — no mask buffer, no memset, no precursor
// kernels). Row sets are disjoint -> no race; every output element written.
__global__ __launch_bounds__(256, 4)
void sparse_linear_kernel(const float* __restrict__ x,
                          const float* __restrict__ w,
                          const float* __restrict__ bias,
                          const int* __restrict__ cidx,
                          float* __restrict__ out)
{
    __shared__ char lds[(BM + BN) * BK * 2];   // A 8KB + B 16KB, bf16, swizzled

    const int tid  = threadIdx.x;
    const int lane = tid & 63;
    const int wid  = tid >> 6;

    if (blockIdx.x >= GEMM_BLOCKS) {
        // ---- zero-writer path: each wave owns a row; all 64 lanes do the
        // same binary search (uniform -> broadcast L2 loads), then write
        // 768 floats as 3 x f32x4 per lane.
        int zw = (blockIdx.x - GEMM_BLOCKS) * 4 + wid;
        for (int row = zw; row < TOT_ROWS; row += ZBLOCKS * 4) {
            int n = row >> 12;            // row / C_C
            int c = row & (C_C - 1);
            const int* a = cidx + (n << 10);
            int lo = 0, hi = K_K;
            while (lo < hi) {
                int mid = (lo + hi) >> 1;
                int v = a[mid];
                lo = (v < c) ? mid + 1 : lo;
                hi = (v < c) ? hi : mid;
            }
            bool present = (lo < K_K) && (a[lo] == c);
            if (!present) {
                float* o = out + (size_t)row * O_O;
                f32x4 z = {0.f, 0.f, 0.f, 0.f};
                #pragma unroll
                for (int k2 = 0; k2 < 3; ++k2)
                    *reinterpret_cast<f32x4*>(o + (lane + k2 * 64) * 4) = z;
            }
        }
        return;
    }

    // ---- GEMM path ----
    // XCD-chunked swizzle: blockIdx b -> XCD b%8 (HW round-robin); give each
    // XCD a contiguous bm-major chunk so its A rows (3.1MB) + W (2.4MB)
    // stay L2-resident.
    const int logical = (blockIdx.x & 7) * XCD_CHUNK + (blockIdx.x >> 3);
    const int bm = logical / GBN;
    const int bn = logical % GBN;

    char* Asb = lds;                   // [64][64] bf16, row stride 128 B
    char* Bsb = lds + BM * BK * 2;     // [128][64]

    const int wr = wid >> 1;           // wave row 0..1 (32-row half)
    const int wc = wid & 1;            // wave col 0..1 (64-col half)

    const int sr = tid >> 4;           // staging row-in-pass 0..15
    const int sc = tid & 15;           // staging float4 col 0..15

    // Fixed per-thread source offsets
    int aoff[4];
    int boff[8];
    #pragma unroll
    for (int p = 0; p < 4; ++p) {
        int row = p * 16 + sr;                  // 0..63
        int m = bm * BM + row;
        int n = m >> 10;
        int src = cidx[m];
        aoff[p] = (n * C_C + src) * H_H + sc * 4;
    }
    #pragma unroll
    for (int p = 0; p < 8; ++p) {
        int row = p * 16 + sr;                  // 0..127
        boff[p] = (bn * BN + row) * H_H + sc * 4;
    }

    const int wsw = (sc * 8) ^ ((sr & 7) << 4);   // LDS write swizzle

    // Prologue: K-step 0 into registers
    f32x4 av[4], bv[8];
    #pragma unroll
    for (int p = 0; p < 4; ++p) av[p] = *reinterpret_cast<const f32x4*>(x + aoff[p]);
    #pragma unroll
    for (int p = 0; p < 8; ++p) bv[p] = *reinterpret_cast<const f32x4*>(w + boff[p]);

    f32x4 acc[2][4];
    #pragma unroll
    for (int i = 0; i < 2; ++i)
        #pragma unroll
        for (int j = 0; j < 4; ++j)
            acc[i][j] = (f32x4){0.f, 0.f, 0.f, 0.f};

    const int frow = lane & 15;
    const int fkb  = (lane >> 4) * 16;     // k-part byte offset (8 bf16)

    for (int kt = 0; kt < NT; ++kt) {
        __syncthreads();
        #pragma unroll
        for (int p = 0; p < 4; ++p) {
            int row = p * 16 + sr;
            ushort4v pa;
            pa.x = f2bf(av[p].x); pa.y = f2bf(av[p].y);
            pa.z = f2bf(av[p].z); pa.w = f2bf(av[p].w);
            *reinterpret_cast<ushort4v*>(Asb + row * 128 + wsw) = pa;
        }
        #pragma unroll
        for (int p = 0; p < 8; ++p) {
            int row = p * 16 + sr;
            ushort4v pb;
            pb.x = f2bf(bv[p].x); pb.y = f2bf(bv[p].y);
            pb.z = f2bf(bv[p].z); pb.w = f2bf(bv[p].w);
            *reinterpret_cast<ushort4v*>(Bsb + row * 128 + wsw) = pb;
        }
        __syncthreads();

        // T14: issue next tile's global loads before compute
        if (kt + 1 < NT) {
            const int kbase = (kt + 1) * BK;
            #pragma unroll
            for (int p = 0; p < 4; ++p)
                av[p] = *reinterpret_cast<const f32x4*>(x + aoff[p] + kbase);
            #pragma unroll
            for (int p = 0; p < 8; ++p)
                bv[p] = *reinterpret_cast<const f32x4*>(w + boff[p] + kbase);
        }

        #pragma unroll
        for (int kk = 0; kk < 2; ++kk) {
            short8 af[2], bf_[4];
            const int kbyte = kk * 64 + fkb;
            #pragma unroll
            for (int mi = 0; mi < 2; ++mi) {
                int row = wr * 32 + mi * 16 + frow;
                af[mi] = *reinterpret_cast<const short8*>(
                    Asb + row * 128 + (kbyte ^ ((row & 7) << 4)));
            }
            #pragma unroll
            for (int nj = 0; nj < 4; ++nj) {
                int row = wc * 64 + nj * 16 + frow;
                bf_[nj] = *reinterpret_cast<const short8*>(
                    Bsb + row * 128 + (kbyte ^ ((row & 7) << 4)));
            }
            #pragma unroll
            for (int mi = 0; mi < 2; ++mi)
                #pragma unroll
                for (int nj = 0; nj < 4; ++nj)
                    acc[mi][nj] = __builtin_amdgcn_mfma_f32_16x16x32_bf16(
                        af[mi], bf_[nj], acc[mi][nj], 0, 0, 0);
        }
    }

    // ---- epilogue: scatter rows with bias ----
    const int cbase = bn * BN + wc * 64 + frow;
    float biasv[4];
    #pragma unroll
    for (int nj = 0; nj < 4; ++nj) biasv[nj] = bias[cbase + nj * 16];

    #pragma unroll
    for (int mi = 0; mi < 2; ++mi) {
        #pragma unroll
        for (int r = 0; r < 4; ++r) {
            int grow = bm * BM + wr * 32 + mi * 16 + (lane >> 4) * 4 + r;
            int n = grow >> 10;
            int src = cidx[grow];
            size_t obase = ((size_t)(n * C_C + src)) * O_O;
            #pragma unroll
            for (int nj = 0; nj < 4; ++nj)
                out[obase + cbase + nj * 16] = acc[mi][nj][r] + biasv[nj];
        }
    }
}

extern "C" void kernel_launch(void* const* d_in, const int* in_sizes, int n_in,
                              void* d_out, int out_size, void* d_ws, size_t ws_size,
                              hipStream_t stream) {
    const float* x    = (const float*)d_in[0];
    const float* w    = (const float*)d_in[1];
    const float* bias = (const float*)d_in[2];
    const int*   cidx = (const int*)d_in[3];
    float* out = (float*)d_out;

    sparse_linear_kernel<<<GEMM_BLOCKS + ZBLOCKS, 256, 0, stream>>>(
        x, w, bias, cidx, out);
}